// Round 16
// baseline (601.578 us; speedup 1.0000x reference)
//
#include <hip/hip_runtime.h>
#include <hip/hip_bf16.h>
#include <math.h>

// ---------------------------------------------------------------------------
// Model constants
//   B=4, T=1024, F_IN=80, C0=256, C_EMB=512, HEADS=8, K=7, D_HEAD=64, MLP=2048
// ---------------------------------------------------------------------------

typedef __bf16 bf16x8 __attribute__((ext_vector_type(8)));
typedef float f32x4 __attribute__((ext_vector_type(4)));

static __device__ __forceinline__ short f2bf(float f) {
  __hip_bfloat16 h = __float2bfloat16(f);
  return __builtin_bit_cast(short, h);
}

static __device__ __forceinline__ float wave_sum(float v) {
#pragma unroll
  for (int o = 32; o; o >>= 1) v += __shfl_xor(v, o);
  return v;
}

// async global->LDS, 16B per lane; dest = lds_base (wave-uniform) + lane*16
static __device__ __forceinline__ void gld16(const void* g, void* l) {
  __builtin_amdgcn_global_load_lds(
      (const __attribute__((address_space(1))) unsigned int*)g,
      (__attribute__((address_space(3))) unsigned int*)l, 16, 0, 0);
}

// ---------------------------------------------------------------------------
// conv0 (1->256, 3x3, pad t +-1) + maxpool3(w) + relu.  x:[4,1,1024,80] fp32
// out h0 bf16 [b][cc8][t1024][w28][unit4^swz][8]  (w=26,27 zero pads; conv1's
// X stage is uniform wave-loads; units swizzled for conflict-free reads)
// ---------------------------------------------------------------------------
__global__ __launch_bounds__(256) void conv0_kernel(
    const float* __restrict__ x, const float* __restrict__ w,
    const float* __restrict__ bias, short* __restrict__ h0) {
  const int b = blockIdx.x >> 10;
  const int t = blockIdx.x & 1023;
  const int c = threadIdx.x;
  __shared__ float xs[3][80];
  for (int i = threadIdx.x; i < 240; i += 256) {
    int dt = i / 80, f = i - dt * 80;
    int tt = t + dt - 1;
    xs[dt][f] = (tt >= 0 && tt < 1024) ? x[(b * 1024 + tt) * 80 + f] : 0.f;
  }
  float wr[9];
#pragma unroll
  for (int i = 0; i < 9; ++i) wr[i] = w[c * 9 + i];
  const float bi = bias[c];
  __syncthreads();
  const int cc = c >> 5, q = (c >> 3) & 3, e = c & 7;
  short* outb = &h0[((size_t)(b * 8 + cc) * 1024 + t) * 896];
  for (int fo = 0; fo < 26; ++fo) {
    float m = -1e30f;
#pragma unroll
    for (int p = 0; p < 3; ++p) {
      const int f = fo * 3 + p;
      float acc = bi;
#pragma unroll
      for (int dt = 0; dt < 3; ++dt)
#pragma unroll
        for (int df = 0; df < 3; ++df)
          acc += xs[dt][f + df] * wr[dt * 3 + df];
      m = fmaxf(m, acc);
    }
    const int row = t * 28 + fo;
    outb[fo * 32 + (q ^ ((row >> 1) & 3)) * 8 + e] = f2bf(fmaxf(m, 0.f));
  }
  if (c < 64) outb[832 + c] = 0;  // zero pad rows w=26,27
}

// ---------------------------------------------------------------------------
// Weight pre-transposes (fp32 -> bf16, once per launch)
// ---------------------------------------------------------------------------
// conv1_w [co512][ci256][1][kw12] -> wt1 [cc8][kw12][co512][unit4^swz][8]
__global__ __launch_bounds__(256) void prep_w1(const float* __restrict__ w,
                                               short* __restrict__ wt) {
  const int co = blockIdx.x;
  __shared__ float ls[3072];
  for (int i = threadIdx.x; i < 3072; i += 256) ls[i] = w[co * 3072 + i];
  __syncthreads();
  const int swz = (co >> 1) & 3;
  for (int i = threadIdx.x; i < 3072; i += 256) {
    const int e = i & 7, q = (i >> 3) & 3, kw = (i >> 5) % 12, cc = i / 384;
    const int ci = cc * 32 + q * 8 + e;
    wt[(((size_t)(cc * 12 + kw) * 512 + co) * 4 + (q ^ swz)) * 8 + e] =
        f2bf(ls[ci * 12 + kw]);
  }
}

// conv2_w [co512][ci512][3][3] -> wt2 [cc16][p9][co512][unit4^swz][8]
__global__ __launch_bounds__(256) void prep_w2(const float* __restrict__ w,
                                               short* __restrict__ wt) {
  const int co = blockIdx.x;
  __shared__ float ls[4608];
  for (int i = threadIdx.x; i < 4608; i += 256) ls[i] = w[co * 4608 + i];
  __syncthreads();
  const int swz = (co >> 1) & 3;
  for (int i = threadIdx.x; i < 4608; i += 256) {
    const int e = i & 7, q = (i >> 3) & 3, p = (i >> 5) % 9, cc = i / 288;
    const int ci = cc * 32 + q * 8 + e;
    wt[(((size_t)(cc * 9 + p) * 512 + co) * 4 + (q ^ swz)) * 8 + e] =
        f2bf(ls[ci * 9 + p]);
  }
}

// ---------------------------------------------------------------------------
// Batched prep: all dense W [K][N] fp32 -> Wt [N][K] bf16 transposes
// (q,k,v,ao,m1,m2 = 3072 32x32 tiles), h1 halo zeroing (64 blocks), and
// qkv bias concat (6 blocks). One launch instead of eight.
// ---------------------------------------------------------------------------
__global__ __launch_bounds__(256) void prep_all(
    const float* __restrict__ q_w, const float* __restrict__ k_w,
    const float* __restrict__ v_w, const float* __restrict__ ao_w,
    const float* __restrict__ m1_w, const float* __restrict__ m2_w,
    const float* __restrict__ q_b, const float* __restrict__ k_b,
    const float* __restrict__ v_b,
    short* __restrict__ wtqkv, short* __restrict__ wtao,
    short* __restrict__ wtm1, short* __restrict__ wtm2,
    float* __restrict__ qkvb, short* __restrict__ h1) {
  const int g = blockIdx.x;
  if (g < 3072) {
    const float* src; short* dst; int K, N, t0;
    if (g < 256)       { src = q_w;  dst = wtqkv;             K = 512;  N = 512;  t0 = g; }
    else if (g < 512)  { src = k_w;  dst = wtqkv + 512 * 512; K = 512;  N = 512;  t0 = g - 256; }
    else if (g < 768)  { src = v_w;  dst = wtqkv + 1024 * 512; K = 512; N = 512;  t0 = g - 512; }
    else if (g < 1024) { src = ao_w; dst = wtao;              K = 512;  N = 512;  t0 = g - 768; }
    else if (g < 2048) { src = m1_w; dst = wtm1;              K = 512;  N = 2048; t0 = g - 1024; }
    else               { src = m2_w; dst = wtm2;              K = 2048; N = 512;  t0 = g - 2048; }
    const int ntn = N >> 5;
    const int kt = t0 / ntn, nt = t0 - kt * ntn;
    const int k0 = kt * 32, n0 = nt * 32;
    __shared__ float tile[32][33];
    const int tx = threadIdx.x & 31, ty = threadIdx.x >> 5;
    for (int r = ty; r < 32; r += 8)
      tile[r][tx] = src[(size_t)(k0 + r) * N + n0 + tx];
    __syncthreads();
    for (int r = ty; r < 32; r += 8)
      dst[(size_t)(n0 + r) * K + k0 + tx] = f2bf(tile[tx][r]);
  } else if (g < 3136) {
    short* base = h1 + (size_t)(g - 3072) * 164160;
    for (int i = threadIdx.x; i < 160; i += 256) {
      base[i] = 0;
      base[1025 * 160 + i] = 0;
    }
  } else {
    const int i = (g - 3136) * 256 + threadIdx.x;  // 0..1535
    qkvb[i] = i < 512 ? q_b[i] : (i < 1024 ? k_b[i - 512] : v_b[i - 1024]);
  }
}

// ---------------------------------------------------------------------------
// conv1 (256->512, 1x12) + pool3 + relu via MFMA GEMM, FINE-PHASE schedule
// at the R13 occupancy point: 512 thr / 8 waves, ONE block/CU (LDS 136KB),
// block tile 128co x 32t, wave tile 64co x 128col. 96 phases (8cc x 12kw):
// {ds-read 12 operand frags -> issue A-prefetch 2-ahead (ring of 3, 1 ld/wave)
//  / X-prefetch 11-ahead (dbuf, 7 ld/wave at kw=0) -> counted vmcnt (8/1/0,
//  derived; prefetch never drained early) -> s_barrier -> setprio(1) ->
//  32 PURE-REGISTER MFMA -> setprio(0) -> s_barrier}.
// __launch_bounds__(512,2) -> VGPR cap 256 (needs ~200; no 128-cap spill).
// h0 [b][cc8][t][w28][unit^swz] -> h1 [b][cc16][tslot1026][w5][unit^swz]
// ---------------------------------------------------------------------------
__global__ __launch_bounds__(512, 2) void conv1_kernel(
    const short* __restrict__ h0, const short* __restrict__ wt1,
    const float* __restrict__ bias, short* __restrict__ h1) {
  const int b = blockIdx.x >> 5;
  const int t0 = (blockIdx.x & 31) * 32;
  const int co0 = blockIdx.y * 128;
  __shared__ short XsF[2][28672];   // 57,344 B each: 896 rows x 4 units
  __shared__ short AsR[3][4096];    // 8,192 B each: 1 kw x 128co x 32ci (ring)
  const int tid = threadIdx.x;
  const int lane = tid & 63;
  const int wid = tid >> 6;
  const int wm = wid >> 2;   // 0..1  (64 co each)
  const int wn = wid & 3;    // 0..3  (8 t each)
  const int l15 = lane & 15, lg = lane >> 4;

  const f32x4 zf = {0.f, 0.f, 0.f, 0.f};
  f32x4 acc[4][8];
#pragma unroll
  for (int i = 0; i < 4; ++i)
#pragma unroll
    for (int j = 0; j < 8; ++j) acc[i][j] = zf;

  auto stageX = [&](int cc, int buf) {
    const short* xs = h0 + ((size_t)(b * 8 + cc) * 1024 + t0) * 896;
#pragma unroll
    for (int i = 0; i < 7; ++i) {
      const int v = wid * 7 + i;   // 0..55, uniform 7 per wave
      gld16(xs + v * 512 + lane * 8, &XsF[buf][v * 512]);
    }
  };
  // stage kw-step s2 (1 load/wave) into ring slot s2%3
  auto stageA = [&](int s2) {
    gld16(wt1 + ((size_t)s2 * 512 + co0) * 32 + wid * 512 + lane * 8,
          &AsR[s2 % 3][wid * 512]);
  };

  stageX(0, 0);
  stageA(0);
  stageA(1);
  asm volatile("s_waitcnt vmcnt(0)" ::: "memory");
  __builtin_amdgcn_s_barrier();

  for (int cc = 0; cc < 8; ++cc) {
#pragma unroll
    for (int kw = 0; kw < 12; ++kw) {
      const int s = cc * 12 + kw;
      const short* Ab = AsR[kw % 3];   // 12%3==0 -> kw%3 == s%3
      const short* Xb = XsF[cc & 1];
      // --- phase part 1: ds-read this phase's operand fragments ---
      bf16x8 a[4], xv[8];
#pragma unroll
      for (int sm = 0; sm < 4; ++sm) {
        const int co_l = wm * 64 + sm * 16 + l15;
        a[sm] = *reinterpret_cast<const bf16x8*>(
            &Ab[(co_l * 4 + (lg ^ ((co_l >> 1) & 3))) * 8]);
      }
#pragma unroll
      for (int sn = 0; sn < 8; ++sn) {
        const int row = (wn * 8 + sn) * 28 + l15 + kw;
        xv[sn] = *reinterpret_cast<const bf16x8*>(
            &Xb[(row * 4 + (lg ^ ((row >> 1) & 3))) * 8]);
      }
      // --- phase part 2: issue prefetch (stays in flight across barriers) ---
      if (s <= 93) stageA(s + 2);
      if (kw == 0 && cc < 7) stageX(cc + 1, (cc + 1) & 1);
      // --- phase part 3: counted wait -- guarantee A(s+1) (+X at chunk edge)
      if (cc < 7 && kw <= 1) {
        asm volatile("s_waitcnt vmcnt(8)" ::: "memory");  // A(s+2)+X7 younger
      } else if (s >= 94) {
        asm volatile("s_waitcnt vmcnt(0)" ::: "memory");  // tail drain
      } else {
        asm volatile("s_waitcnt vmcnt(1)" ::: "memory");  // A(s+2) younger
      }
      __builtin_amdgcn_s_barrier();
      // --- phase part 4: pure-register MFMA cluster under setprio ---
      __builtin_amdgcn_s_setprio(1);
#pragma unroll
      for (int sn = 0; sn < 8; ++sn)
#pragma unroll
        for (int sm = 0; sm < 4; ++sm)
          acc[sm][sn] = __builtin_amdgcn_mfma_f32_16x16x32_bf16(
              a[sm], xv[sn], acc[sm][sn], 0, 0, 0);
      __builtin_amdgcn_s_setprio(0);
      asm volatile("" ::: "memory");
      __builtin_amdgcn_s_barrier();
    }
  }
  // epilogue: pool w-triples (within 16-lane groups) + bias + relu
  const int basel = lane & 48;
  const int wsrc = (l15 < 5) ? 3 * l15 : 0;
#pragma unroll
  for (int sm = 0; sm < 4; ++sm)
#pragma unroll
    for (int sn = 0; sn < 8; ++sn) {
      const int t = t0 + wn * 8 + sn;
#pragma unroll
      for (int r = 0; r < 4; ++r) {
        float val = acc[sm][sn][r];
        float v0 = __shfl(val, basel + wsrc);
        float v1 = __shfl(val, basel + wsrc + 1);
        float v2 = __shfl(val, basel + wsrc + 2);
        if (l15 < 5) {
          const int co = co0 + wm * 64 + sm * 16 + lg * 4 + r;
          float p = fmaxf(fmaxf(v0, v1), v2) + bias[co];
          const int cc2 = co >> 5, q = (co >> 3) & 3, e = co & 7;
          const int row_g = (t + 1) * 5 + l15;
          h1[((size_t)(b * 16 + cc2) * 1026 + (t + 1)) * 160 + l15 * 32 +
             (q ^ ((row_g >> 1) & 3)) * 8 + e] = f2bf(fmaxf(p, 0.f));
        }
      }
    }
}

// ---------------------------------------------------------------------------
// conv2 (512->512, 3x3, pad t +-1) + pool3 + relu, counted-vmcnt pipeline ->
// emb_in fp32 [b][t][512].
// ---------------------------------------------------------------------------
__global__ __launch_bounds__(512) void conv2_kernel(
    const short* __restrict__ h1, const short* __restrict__ wt2,
    const float* __restrict__ bias, float* __restrict__ emb_in) {
  const int b = blockIdx.x >> 5;
  const int t0 = (blockIdx.x & 31) * 32;
  const int co0 = blockIdx.y * 128;
  __shared__ __align__(16) short smem2[35840];  // 71680 B
  // layout: X buf0 @0, X buf1 @5632, A buf0 @11264, A buf1 @23552 (shorts)
  const int tid = threadIdx.x;
  const int lane = tid & 63;
  const int wid = tid >> 6;
  const int wm = wid >> 1;  // 0..3 (32 co each)
  const int wn = wid & 1;   // 0..1 (48 cols each)
  const int l15 = lane & 15, lg = lane >> 4;
  const f32x4 zf = {0.f, 0.f, 0.f, 0.f};
  f32x4 acc[2][3];
#pragma unroll
  for (int i = 0; i < 2; ++i)
#pragma unroll
    for (int j = 0; j < 3; ++j) acc[i][j] = zf;
  int tl[3], dwl[3];
#pragma unroll
  for (int sn = 0; sn < 3; ++sn) {
    const int c = wn * 48 + sn * 16 + l15;
    tl[sn] = c / 3;
    dwl[sn] = c - tl[sn] * 3;
  }

  auto stageX = [&](int cc, int buf) {
    const short* xs = h1 + ((size_t)(b * 16 + cc) * 1026 + t0) * 160;
#pragma unroll
    for (int i = 0; i < 2; ++i) {
      const int v = wid + 8 * i;
      if (v < 11) gld16(xs + v * 512 + lane * 8, &smem2[buf * 5632 + v * 512]);
    }
  };
  auto stageA = [&](int cc, int g, int buf) {
#pragma unroll
    for (int i = 0; i < 3; ++i) {
      const int u = wid * 3 + i;      // 0..23, uniform 3 per wave
      const int pl = u >> 3, r = u & 7;
      gld16(wt2 + ((size_t)((cc * 9 + g * 3 + pl) * 512) + co0) * 32 +
                r * 512 + lane * 8,
            &smem2[11264 + buf * 12288 + pl * 4096 + r * 512]);
    }
  };

  stageX(0, 0);
  stageA(0, 0, 0);
  asm volatile("s_waitcnt vmcnt(0)" ::: "memory");
  __builtin_amdgcn_s_barrier();

  for (int s = 0; s < 48; ++s) {
    const int cc = s / 3, g = s - cc * 3;
    if (s < 47) {
      const int s1 = s + 1;
      const int cc1 = s1 / 3, g1 = s1 - cc1 * 3;
      stageA(cc1, g1, s1 & 1);
      if (g1 == 0) {
        stageX(cc1, cc1 & 1);
        if (wid < 3) asm volatile("s_waitcnt vmcnt(5)" ::: "memory");  // 3A+2X
        else         asm volatile("s_waitcnt vmcnt(4)" ::: "memory");  // 3A+1X
      } else {
        asm volatile("s_waitcnt vmcnt(3)" ::: "memory");               // 3A
      }
    } else {
      asm volatile("s_waitcnt vmcnt(0)" ::: "memory");
    }
    __builtin_amdgcn_s_barrier();
    const short* Xb = &smem2[(cc & 1) * 5632];
    const short* Ab = &smem2[11264 + (s & 1) * 12288];
#pragma unroll
    for (int j = 0; j < 3; ++j) {   // p = g*3+j -> dt=g, dw=j
      bf16x8 a[2];
#pragma unroll
      for (int sm = 0; sm < 2; ++sm) {
        const int co_l = wm * 32 + sm * 16 + l15;
        a[sm] = *reinterpret_cast<const bf16x8*>(
            &Ab[(j * 512 + co_l * 4 + (lg ^ ((co_l >> 1) & 3))) * 8]);
      }
#pragma unroll
      for (int sn = 0; sn < 3; ++sn) {
        const int row = (tl[sn] + g) * 5 + dwl[sn] + j;
        bf16x8 xv = *reinterpret_cast<const bf16x8*>(
            &Xb[(row * 4 + (lg ^ ((row >> 1) & 3))) * 8]);
#pragma unroll
        for (int sm = 0; sm < 2; ++sm)
          acc[sm][sn] = __builtin_amdgcn_mfma_f32_16x16x32_bf16(a[sm], xv, acc[sm][sn], 0, 0, 0);
      }
    }
    asm volatile("" ::: "memory");
    __builtin_amdgcn_s_barrier();
  }
  float(*Ds)[100] = reinterpret_cast<float(*)[100]>(smem2);  // epilogue overlay
#pragma unroll
  for (int sm = 0; sm < 2; ++sm)
#pragma unroll
    for (int sn = 0; sn < 3; ++sn)
#pragma unroll
      for (int r = 0; r < 4; ++r)
        Ds[wm * 32 + sm * 16 + lg * 4 + r][wn * 48 + sn * 16 + l15] = acc[sm][sn][r];
  __syncthreads();
  for (int e = tid; e < 4096; e += 512) {
    const int co = e & 127, tt = e >> 7;
    float m = fmaxf(fmaxf(Ds[co][tt * 3], Ds[co][tt * 3 + 1]), Ds[co][tt * 3 + 2]) + bias[co0 + co];
    emb_in[((size_t)(b * 1024) + t0 + tt) * 512 + co0 + co] = fmaxf(m, 0.f);
  }
}

// ---------------------------------------------------------------------------
// LayerNorm kernels. wave-per-row (512 cols, 8 per lane).
// ln_double: x -> emb (fp32, residual) and hs1 (bf16, GEMM A input)
// ---------------------------------------------------------------------------
__global__ __launch_bounds__(256) void ln_double_kernel(
    const float* __restrict__ x, const float* __restrict__ g0,
    const float* __restrict__ b0, const float* __restrict__ g1,
    const float* __restrict__ b1, float* __restrict__ o0, short* __restrict__ o1) {
  const int row = blockIdx.x * 4 + (threadIdx.x >> 6);
  const int lane = threadIdx.x & 63;
  const float* xr = x + (size_t)row * 512;
  float v[8];
#pragma unroll
  for (int j = 0; j < 8; ++j) v[j] = xr[j * 64 + lane];
  float s = 0;
#pragma unroll
  for (int j = 0; j < 8; ++j) s += v[j];
  s = wave_sum(s);
  const float mean = s * (1.f / 512.f);
  float q = 0;
#pragma unroll
  for (int j = 0; j < 8; ++j) { float d = v[j] - mean; q += d * d; }
  q = wave_sum(q);
  const float rs = rsqrtf(q * (1.f / 512.f) + 1e-5f);
#pragma unroll
  for (int j = 0; j < 8; ++j) {
    const int ci = j * 64 + lane;
    float e = (v[j] - mean) * rs * g0[ci] + b0[ci];
    o0[(size_t)row * 512 + ci] = e;
    v[j] = e;
  }
  s = 0;
#pragma unroll
  for (int j = 0; j < 8; ++j) s += v[j];
  s = wave_sum(s);
  const float mean2 = s * (1.f / 512.f);
  q = 0;
#pragma unroll
  for (int j = 0; j < 8; ++j) { float d = v[j] - mean2; q += d * d; }
  q = wave_sum(q);
  const float rs2 = rsqrtf(q * (1.f / 512.f) + 1e-5f);
#pragma unroll
  for (int j = 0; j < 8; ++j) {
    const int ci = j * 64 + lane;
    o1[(size_t)row * 512 + ci] = f2bf((v[j] - mean2) * rs2 * g1[ci] + b1[ci]);
  }
}

__global__ __launch_bounds__(256) void ln_kernel(
    const float* __restrict__ x, const float* __restrict__ g,
    const float* __restrict__ b, short* __restrict__ o) {
  const int row = blockIdx.x * 4 + (threadIdx.x >> 6);
  const int lane = threadIdx.x & 63;
  const float* xr = x + (size_t)row * 512;
  float v[8];
#pragma unroll
  for (int j = 0; j < 8; ++j) v[j] = xr[j * 64 + lane];
  float s = 0;
#pragma unroll
  for (int j = 0; j < 8; ++j) s += v[j];
  s = wave_sum(s);
  const float mean = s * (1.f / 512.f);
  float q = 0;
#pragma unroll
  for (int j = 0; j < 8; ++j) { float d = v[j] - mean; q += d * d; }
  q = wave_sum(q);
  const float rs = rsqrtf(q * (1.f / 512.f) + 1e-5f);
#pragma unroll
  for (int j = 0; j < 8; ++j) {
    const int ci = j * 64 + lane;
    o[(size_t)row * 512 + ci] = f2bf((v[j] - mean) * rs * g[ci] + b[ci]);
  }
}

// ---------------------------------------------------------------------------
// 1D neighborhood attention (K=7) with rpb. qkv fp32 [b][t][1536]
// (q at +0 pre-scaled 1/8, k at +512, v at +1024). wave per (b,h,t); lane=d.
// ctx output bf16 (feeds attn-out GEMM).
// ---------------------------------------------------------------------------
__global__ __launch_bounds__(256) void na1d_kernel(
    const float* __restrict__ qkv, const float* __restrict__ rpb,
    short* __restrict__ ctx) {
  const int W = blockIdx.x * 4 + (threadIdx.x >> 6);
  const int lane = threadIdx.x & 63;
  const int b = W >> 13, h = (W >> 10) & 7, t = W & 1023;
  int ni = t - 3;
  ni = ni < 0 ? 0 : (ni > 1017 ? 1017 : ni);
  const float qv = qkv[((size_t)(b * 1024) + t) * 1536 + h * 64 + lane];
  const float* kb = qkv + 512 + ((size_t)(b * 1024) + ni) * 1536 + h * 64;
  float s[7];
#pragma unroll
  for (int j = 0; j < 7; ++j) {
    float pd = qv * kb[j * 1536 + lane];
    pd = wave_sum(pd);
    s[j] = pd + rpb[h * 13 + (ni + j - t + 6)];
  }
  float mx = s[0];
#pragma unroll
  for (int j = 1; j < 7; ++j) mx = fmaxf(mx, s[j]);
  float den = 0;
#pragma unroll
  for (int j = 0; j < 7; ++j) { s[j] = expf(s[j] - mx); den += s[j]; }
  const float inv = 1.f / den;
  const float* vb = qkv + 1024 + ((size_t)(b * 1024) + ni) * 1536 + h * 64;
  float o = 0;
#pragma unroll
  for (int j = 0; j < 7; ++j) o += s[j] * vb[j * 1536 + lane];
  ctx[((size_t)(b * 1024) + t) * 512 + h * 64 + lane] = f2bf(o * inv);
}

// ---------------------------------------------------------------------------
// Transformer GEMM, bf16 A: C[M=4096][N] = A[M][K](bf16) x Wt[N][K](bf16).
// Tile 128x64, 4 waves 2x2, BK=64, counted-vmcnt double-buffer, gld16 staging
// with consumer-side XOR pre-swizzle. LDS 48KB -> 3 blocks/CU.
// EPI: 2 = bias+gelu -> bf16 out, 3 = bias+residual -> f32,
//      4 = bias, *0.125 if n<512 -> f32 (fused qkv).
// ---------------------------------------------------------------------------
template <int EPI>
__global__ __launch_bounds__(256) void gemm_bf(
    const short* __restrict__ A, const short* __restrict__ Wt,
    const float* __restrict__ bias, const float* __restrict__ res,
    void* __restrict__ Cv, int K, int N) {
  const int m0 = blockIdx.x * 128, n0 = blockIdx.y * 64;
  __shared__ short Asm[2][8192];   // [128 rows][64 k] linear, 16KB each
  __shared__ short Bsm[2][4096];   // [64 rows][64 k] linear, 8KB each
  const int tid = threadIdx.x;
  const int wid = tid >> 6, lane = tid & 63;
  const int wm = wid >> 1, wn = wid & 1;
  const int l15 = lane & 15, lg = lane >> 4;
  const int srow = lane >> 3, su = lane & 7;          // staging roles
  const int ssw = (su ^ srow) << 3;                   // pre-swizzled k-unit (shorts)
  const f32x4 zf = {0.f, 0.f, 0.f, 0.f};
  f32x4 acc[4][2];
#pragma unroll
  for (int i = 0; i < 4; ++i) { acc[i][0] = zf; acc[i][1] = zf; }

  auto stage = [&](int k0, int buf) {
#pragma unroll
    for (int i = 0; i < 4; ++i) {                      // A: rows 8/call
      const int r0 = (wid * 4 + i) * 8;                // 0,8,...,120
      gld16(A + (size_t)(m0 + r0 + srow) * K + k0 + ssw, &Asm[buf][r0 * 64]);
    }
#pragma unroll
    for (int i = 0; i < 2; ++i) {                      // B: rows 8/call
      const int r0 = (wid * 2 + i) * 8;                // 0,8,...,56
      gld16(Wt + (size_t)(n0 + r0 + srow) * K + k0 + ssw, &Bsm[buf][r0 * 64]);
    }
  };

  const int S = K >> 6;
  stage(0, 0);
  asm volatile("s_waitcnt vmcnt(0)" ::: "memory");
  __builtin_amdgcn_s_barrier();

  for (int s = 0; s < S; ++s) {
    if (s < S - 1) {
      stage((s + 1) << 6, (s + 1) & 1);
      asm volatile("s_waitcnt vmcnt(6)" ::: "memory");
    } else {
      asm volatile("s_waitcnt vmcnt(0)" ::: "memory");
    }
    __builtin_amdgcn_s_barrier();
    const short* Ab = Asm[s & 1];
    const short* Bb = Bsm[s & 1];
#pragma unroll
    for (int kk = 0; kk < 2; ++kk) {
      const int u = kk * 4 + lg;
      bf16x8 bfr[2];
#pragma unroll
      for (int sn = 0; sn < 2; ++sn) {
        const int rn = wn * 32 + sn * 16 + l15;
        bfr[sn] = *reinterpret_cast<const bf16x8*>(&Bb[rn * 64 + ((u ^ (rn & 7)) << 3)]);
      }
#pragma unroll
      for (int sm = 0; sm < 4; ++sm) {
        const int rm = wm * 64 + sm * 16 + l15;
        bf16x8 a = *reinterpret_cast<const bf16x8*>(&Ab[rm * 64 + ((u ^ (rm & 7)) << 3)]);
#pragma unroll
        for (int sn = 0; sn < 2; ++sn)
          acc[sm][sn] = __builtin_amdgcn_mfma_f32_16x16x32_bf16(a, bfr[sn], acc[sm][sn], 0, 0, 0);
      }
    }
    asm volatile("" ::: "memory");
    __builtin_amdgcn_s_barrier();
  }
#pragma unroll
  for (int sm = 0; sm < 4; ++sm)
#pragma unroll
    for (int sn = 0; sn < 2; ++sn)
#pragma unroll
      for (int r = 0; r < 4; ++r) {
        const int m = m0 + wm * 64 + sm * 16 + lg * 4 + r;
        const int n = n0 + wn * 32 + sn * 16 + l15;
        float val = acc[sm][sn][r] + bias[n];
        if (EPI == 2) {
          val = 0.5f * val * (1.f + erff(val * 0.70710678f));
          ((short*)Cv)[(size_t)m * N + n] = f2bf(val);
        } else {
          if (EPI == 3) val += res[(size_t)m * N + n];
          if (EPI == 4 && n < 512) val *= 0.125f;
          ((float*)Cv)[(size_t)m * N + n] = val;
        }
      }
}

// ---------------------------------------------------------------------------
extern "C" void kernel_launch(void* const* d_in, const int* in_sizes, int n_in,
                              void* d_out, int out_size, void* d_ws, size_t ws_size,
                              hipStream_t stream) {
  (void)in_sizes; (void)n_in; (void)out_size;
  const float* x        = (const float*)d_in[0];
  const float* conv0_w  = (const float*)d_in[1];
  const float* conv0_b  = (const float*)d_in[2];
  const float* conv1_w  = (const float*)d_in[3];
  const float* conv1_b  = (const float*)d_in[4];
  const float* conv2_w  = (const float*)d_in[5];
  const float* conv2_b  = (const float*)d_in[6];
  const float* emb_ln_g = (const float*)d_in[7];
  const float* emb_ln_b = (const float*)d_in[8];
  const float* q_w  = (const float*)d_in[9];
  const float* q_b  = (const float*)d_in[10];
  const float* k_w  = (const float*)d_in[11];
  const float* k_b  = (const float*)d_in[12];
  const float* v_w  = (const float*)d_in[13];
  const float* v_b  = (const float*)d_in[14];
  const float* rpb  = (const float*)d_in[15];
  const float* ao_w = (const float*)d_in[16];
  const float* ao_b = (const float*)d_in[17];
  const float* ln1_g = (const float*)d_in[18];
  const float* ln1_b = (const float*)d_in[19];
  const float* ln2_g = (const float*)d_in[20];
  const float* ln2_b = (const float*)d_in[21];
  const float* m1_w = (const float*)d_in[22];
  const float* m1_b = (const float*)d_in[23];
  const float* m2_w = (const float*)d_in[24];
  const float* m2_b = (const float*)d_in[25];

  char* ws = (char*)d_ws;
  size_t off = 0;
  auto alloc = [&](size_t bytes) -> char* {
    char* p = ws + off;
    off += (bytes + 255) & ~(size_t)255;
    return p;
  };
  short* h0   = (short*)alloc(4ull * 8 * 1024 * 896 * 2);     // 58.7 MB
  short* h1   = (short*)alloc(4ull * 16 * 1026 * 160 * 2);    // 21.0 MB
  float* embi = (float*)alloc(4ull * 1024 * 512 * 4);
  float* emb  = (float*)alloc(4ull * 1024 * 512 * 4);
  short* hs1  = (short*)alloc(4ull * 1024 * 512 * 2);         // bf16 GEMM A
  float* qkv  = (float*)alloc(4ull * 1024 * 1536 * 4);        // 25.2 MB
  short* ctx  = (short*)alloc(4ull * 1024 * 512 * 2);         // bf16
  float* hs   = (float*)alloc(4ull * 1024 * 512 * 4);
  short* wt1  = (short*)alloc(512ull * 12 * 256 * 2);
  short* wt2  = (short*)alloc(512ull * 9 * 512 * 2);
  short* wtqkv = (short*)alloc(1536ull * 512 * 2);
  short* wtao = (short*)alloc(512ull * 512 * 2);
  short* wtm1 = (short*)alloc(2048ull * 512 * 2);
  short* wtm2 = (short*)alloc(512ull * 2048 * 2);
  float* qkvb = (float*)alloc(1536ull * 4);
  if (ws_size < off) return;  // fail visibly (poisoned output) instead of OOB
  short* mid  = (short*)h0;   // bf16 [4096][2048] = 16.8MB <= 58.7, h0 dead
  short* ln2o = (short*)embi; // bf16 [4096][512] = 4.2MB <= 8.4, embi dead
  float* outp = (float*)d_out;

  prep_w1<<<512, 256, 0, stream>>>(conv1_w, wt1);
  prep_w2<<<512, 256, 0, stream>>>(conv2_w, wt2);
  prep_all<<<3142, 256, 0, stream>>>(q_w, k_w, v_w, ao_w, m1_w, m2_w,
                                     q_b, k_b, v_b,
                                     wtqkv, wtao, wtm1, wtm2, qkvb, h1);

  conv0_kernel<<<4096, 256, 0, stream>>>(x, conv0_w, conv0_b, h0);
  conv1_kernel<<<dim3(128, 4), 512, 0, stream>>>(h0, wt1, conv1_b, h1);
  conv2_kernel<<<dim3(128, 4), 512, 0, stream>>>(h1, wt2, conv2_b, embi);
  ln_double_kernel<<<1024, 256, 0, stream>>>(embi, emb_ln_g, emb_ln_b, ln1_g, ln1_b, emb, hs1);
  gemm_bf<4><<<dim3(32, 24), 256, 0, stream>>>(hs1, wtqkv, qkvb, nullptr, qkv, 512, 1536);
  na1d_kernel<<<8192, 256, 0, stream>>>(qkv, rpb, ctx);
  gemm_bf<3><<<dim3(32, 8), 256, 0, stream>>>(ctx, wtao, ao_b, emb, hs, 512, 512);
  ln_kernel<<<1024, 256, 0, stream>>>(hs, ln2_g, ln2_b, ln2o);
  gemm_bf<2><<<dim3(32, 32), 256, 0, stream>>>(ln2o, wtm1, m1_b, nullptr, mid, 512, 2048);
  gemm_bf<3><<<dim3(32, 8), 256, 0, stream>>>(mid, wtm2, m2_b, hs, outp, 2048, 512);
}

// Round 17
// 402.694 us; speedup vs baseline: 1.4939x; 1.4939x over previous
//
#include <hip/hip_runtime.h>
#include <hip/hip_bf16.h>
#include <math.h>

// ---------------------------------------------------------------------------
// Model constants
//   B=4, T=1024, F_IN=80, C0=256, C_EMB=512, HEADS=8, K=7, D_HEAD=64, MLP=2048
// ---------------------------------------------------------------------------

typedef __bf16 bf16x8 __attribute__((ext_vector_type(8)));
typedef float f32x4 __attribute__((ext_vector_type(4)));

static __device__ __forceinline__ short f2bf(float f) {
  __hip_bfloat16 h = __float2bfloat16(f);
  return __builtin_bit_cast(short, h);
}

static __device__ __forceinline__ float wave_sum(float v) {
#pragma unroll
  for (int o = 32; o; o >>= 1) v += __shfl_xor(v, o);
  return v;
}

// async global->LDS, 16B per lane; dest = lds_base (wave-uniform) + lane*16
static __device__ __forceinline__ void gld16(const void* g, void* l) {
  __builtin_amdgcn_global_load_lds(
      (const __attribute__((address_space(1))) unsigned int*)g,
      (__attribute__((address_space(3))) unsigned int*)l, 16, 0, 0);
}

// ---------------------------------------------------------------------------
// conv0 (1->256, 3x3, pad t +-1) + maxpool3(w) + relu.  x:[4,1,1024,80] fp32
// out h0 bf16 [b][cc8][t1024][w28][unit4^swz][8]  (w=26,27 zero pads; conv1's
// X stage is uniform wave-loads; units swizzled for conflict-free reads)
// ---------------------------------------------------------------------------
__global__ __launch_bounds__(256) void conv0_kernel(
    const float* __restrict__ x, const float* __restrict__ w,
    const float* __restrict__ bias, short* __restrict__ h0) {
  const int b = blockIdx.x >> 10;
  const int t = blockIdx.x & 1023;
  const int c = threadIdx.x;
  __shared__ float xs[3][80];
  for (int i = threadIdx.x; i < 240; i += 256) {
    int dt = i / 80, f = i - dt * 80;
    int tt = t + dt - 1;
    xs[dt][f] = (tt >= 0 && tt < 1024) ? x[(b * 1024 + tt) * 80 + f] : 0.f;
  }
  float wr[9];
#pragma unroll
  for (int i = 0; i < 9; ++i) wr[i] = w[c * 9 + i];
  const float bi = bias[c];
  __syncthreads();
  const int cc = c >> 5, q = (c >> 3) & 3, e = c & 7;
  short* outb = &h0[((size_t)(b * 8 + cc) * 1024 + t) * 896];
  for (int fo = 0; fo < 26; ++fo) {
    float m = -1e30f;
#pragma unroll
    for (int p = 0; p < 3; ++p) {
      const int f = fo * 3 + p;
      float acc = bi;
#pragma unroll
      for (int dt = 0; dt < 3; ++dt)
#pragma unroll
        for (int df = 0; df < 3; ++df)
          acc += xs[dt][f + df] * wr[dt * 3 + df];
      m = fmaxf(m, acc);
    }
    const int row = t * 28 + fo;
    outb[fo * 32 + (q ^ ((row >> 1) & 3)) * 8 + e] = f2bf(fmaxf(m, 0.f));
  }
  if (c < 64) outb[832 + c] = 0;  // zero pad rows w=26,27
}

// ---------------------------------------------------------------------------
// Weight pre-transposes (fp32 -> bf16, once per launch)
// ---------------------------------------------------------------------------
// conv1_w [co512][ci256][1][kw12] -> wt1 [cc8][kw12][co512][unit4^swz][8]
__global__ __launch_bounds__(256) void prep_w1(const float* __restrict__ w,
                                               short* __restrict__ wt) {
  const int co = blockIdx.x;
  __shared__ float ls[3072];
  for (int i = threadIdx.x; i < 3072; i += 256) ls[i] = w[co * 3072 + i];
  __syncthreads();
  const int swz = (co >> 1) & 3;
  for (int i = threadIdx.x; i < 3072; i += 256) {
    const int e = i & 7, q = (i >> 3) & 3, kw = (i >> 5) % 12, cc = i / 384;
    const int ci = cc * 32 + q * 8 + e;
    wt[(((size_t)(cc * 12 + kw) * 512 + co) * 4 + (q ^ swz)) * 8 + e] =
        f2bf(ls[ci * 12 + kw]);
  }
}

// conv2_w [co512][ci512][3][3] -> wt2 [cc16][p9][co512][unit4^swz][8]
__global__ __launch_bounds__(256) void prep_w2(const float* __restrict__ w,
                                               short* __restrict__ wt) {
  const int co = blockIdx.x;
  __shared__ float ls[4608];
  for (int i = threadIdx.x; i < 4608; i += 256) ls[i] = w[co * 4608 + i];
  __syncthreads();
  const int swz = (co >> 1) & 3;
  for (int i = threadIdx.x; i < 4608; i += 256) {
    const int e = i & 7, q = (i >> 3) & 3, p = (i >> 5) % 9, cc = i / 288;
    const int ci = cc * 32 + q * 8 + e;
    wt[(((size_t)(cc * 9 + p) * 512 + co) * 4 + (q ^ swz)) * 8 + e] =
        f2bf(ls[ci * 9 + p]);
  }
}

// ---------------------------------------------------------------------------
// Batched prep: all dense W [K][N] fp32 -> Wt [N][K] bf16 transposes
// (q,k,v,ao,m1,m2 = 3072 32x32 tiles), h1 halo zeroing (64 blocks), and
// qkv bias concat (6 blocks). One launch instead of eight.
// ---------------------------------------------------------------------------
__global__ __launch_bounds__(256) void prep_all(
    const float* __restrict__ q_w, const float* __restrict__ k_w,
    const float* __restrict__ v_w, const float* __restrict__ ao_w,
    const float* __restrict__ m1_w, const float* __restrict__ m2_w,
    const float* __restrict__ q_b, const float* __restrict__ k_b,
    const float* __restrict__ v_b,
    short* __restrict__ wtqkv, short* __restrict__ wtao,
    short* __restrict__ wtm1, short* __restrict__ wtm2,
    float* __restrict__ qkvb, short* __restrict__ h1) {
  const int g = blockIdx.x;
  if (g < 3072) {
    const float* src; short* dst; int K, N, t0;
    if (g < 256)       { src = q_w;  dst = wtqkv;             K = 512;  N = 512;  t0 = g; }
    else if (g < 512)  { src = k_w;  dst = wtqkv + 512 * 512; K = 512;  N = 512;  t0 = g - 256; }
    else if (g < 768)  { src = v_w;  dst = wtqkv + 1024 * 512; K = 512; N = 512;  t0 = g - 512; }
    else if (g < 1024) { src = ao_w; dst = wtao;              K = 512;  N = 512;  t0 = g - 768; }
    else if (g < 2048) { src = m1_w; dst = wtm1;              K = 512;  N = 2048; t0 = g - 1024; }
    else               { src = m2_w; dst = wtm2;              K = 2048; N = 512;  t0 = g - 2048; }
    const int ntn = N >> 5;
    const int kt = t0 / ntn, nt = t0 - kt * ntn;
    const int k0 = kt * 32, n0 = nt * 32;
    __shared__ float tile[32][33];
    const int tx = threadIdx.x & 31, ty = threadIdx.x >> 5;
    for (int r = ty; r < 32; r += 8)
      tile[r][tx] = src[(size_t)(k0 + r) * N + n0 + tx];
    __syncthreads();
    for (int r = ty; r < 32; r += 8)
      dst[(size_t)(n0 + r) * K + k0 + tx] = f2bf(tile[tx][r]);
  } else if (g < 3136) {
    short* base = h1 + (size_t)(g - 3072) * 164160;
    for (int i = threadIdx.x; i < 160; i += 256) {
      base[i] = 0;
      base[1025 * 160 + i] = 0;
    }
  } else {
    const int i = (g - 3136) * 256 + threadIdx.x;  // 0..1535
    qkvb[i] = i < 512 ? q_b[i] : (i < 1024 ? k_b[i - 512] : v_b[i - 1024]);
  }
}

// ---------------------------------------------------------------------------
// conv1 (256->512, 1x12) + pool3 + relu via MFMA GEMM, counted-vmcnt pipeline.
// (best-measured configuration: 233us, 0 conflicts, no spill, ~885 TF —
// the m97-class structural plateau; 8 schedule variants bracket 230-235us)
// h0 [b][cc8][t][w28][unit^swz] -> h1 [b][cc16][tslot1026][w5][unit^swz]
// Block: co_tile=128, t_tile=32, 8 waves, wave tile 64co x 128col.
// 48 steps (8 ci-chunks x 6 kw-groups of 2); A dbuf counted vmcnt; X
// restaged per chunk. LDS 144KB.
// ---------------------------------------------------------------------------
__global__ __launch_bounds__(512) void conv1_kernel(
    const short* __restrict__ h0, const short* __restrict__ wt1,
    const float* __restrict__ bias, short* __restrict__ h1) {
  const int b = blockIdx.x >> 5;
  const int t0 = (blockIdx.x & 31) * 32;
  const int co0 = blockIdx.y * 128;
  __shared__ short XsF[2][28672];   // 57344 B each: 896 rows x 4 units
  __shared__ short AsF[2][8192];    // 2kw x 512 units
  const int tid = threadIdx.x;
  const int lane = tid & 63;
  const int wid = tid >> 6;
  const int wm = wid >> 2;   // 0..1  (64 co each)
  const int wn = wid & 3;    // 0..3  (8 t each)
  const int l15 = lane & 15, lg = lane >> 4;

  const f32x4 zf = {0.f, 0.f, 0.f, 0.f};
  f32x4 acc[4][8];
#pragma unroll
  for (int i = 0; i < 4; ++i)
#pragma unroll
    for (int j = 0; j < 8; ++j) acc[i][j] = zf;

  auto stageX = [&](int cc, int buf) {
    const short* xs = h0 + ((size_t)(b * 8 + cc) * 1024 + t0) * 896;
#pragma unroll
    for (int i = 0; i < 7; ++i) {
      const int v = wid * 7 + i;   // 0..55, uniform 7 per wave
      gld16(xs + v * 512 + lane * 8, &XsF[buf][v * 512]);
    }
  };
  auto stageA = [&](int cc, int g, int buf) {
#pragma unroll
    for (int i = 0; i < 2; ++i) {
      const int u = wid * 2 + i;      // 0..15, uniform 2 per wave
      const int kwl = u >> 3, r = u & 7;
      gld16(wt1 + ((size_t)((cc * 12 + g * 2 + kwl) * 512) + co0) * 32 +
                r * 512 + lane * 8,
            &AsF[buf][kwl * 4096 + r * 512]);
    }
  };

  stageX(0, 0);
  stageA(0, 0, 0);
  asm volatile("s_waitcnt vmcnt(0)" ::: "memory");
  __builtin_amdgcn_s_barrier();

  for (int s = 0; s < 48; ++s) {
    const int cc = s / 6, g = s - cc * 6;
    if (s < 47) {
      const int s1 = s + 1;
      const int cc1 = s1 / 6, g1 = s1 - cc1 * 6;
      stageA(cc1, g1, s1 & 1);
      if (g1 == 0) {
        stageX(cc1, cc1 & 1);
        asm volatile("s_waitcnt vmcnt(9)" ::: "memory");   // 2 A + 7 X new
      } else {
        asm volatile("s_waitcnt vmcnt(2)" ::: "memory");   // 2 A new
      }
    } else {
      asm volatile("s_waitcnt vmcnt(0)" ::: "memory");
    }
    __builtin_amdgcn_s_barrier();
    const short* Xb = XsF[cc & 1];
    const short* Ab = AsF[s & 1];
#pragma unroll
    for (int j = 0; j < 2; ++j) {
      const int kw = g * 2 + j;
      bf16x8 a[4];
#pragma unroll
      for (int sm = 0; sm < 4; ++sm) {
        const int co_l = wm * 64 + sm * 16 + l15;
        a[sm] = *reinterpret_cast<const bf16x8*>(
            &Ab[(j * 512 + co_l * 4 + (lg ^ ((co_l >> 1) & 3))) * 8]);
      }
#pragma unroll
      for (int sn = 0; sn < 8; ++sn) {
        const int row = (wn * 8 + sn) * 28 + l15 + kw;
        bf16x8 bf = *reinterpret_cast<const bf16x8*>(
            &Xb[(row * 4 + (lg ^ ((row >> 1) & 3))) * 8]);
#pragma unroll
        for (int sm = 0; sm < 4; ++sm)
          acc[sm][sn] = __builtin_amdgcn_mfma_f32_16x16x32_bf16(a[sm], bf, acc[sm][sn], 0, 0, 0);
      }
    }
    asm volatile("" ::: "memory");
    __builtin_amdgcn_s_barrier();
  }
  // epilogue: pool w-triples (within 16-lane groups) + bias + relu
  const int basel = lane & 48;
  const int wsrc = (l15 < 5) ? 3 * l15 : 0;
#pragma unroll
  for (int sm = 0; sm < 4; ++sm)
#pragma unroll
    for (int sn = 0; sn < 8; ++sn) {
      const int t = t0 + wn * 8 + sn;
#pragma unroll
      for (int r = 0; r < 4; ++r) {
        float val = acc[sm][sn][r];
        float v0 = __shfl(val, basel + wsrc);
        float v1 = __shfl(val, basel + wsrc + 1);
        float v2 = __shfl(val, basel + wsrc + 2);
        if (l15 < 5) {
          const int co = co0 + wm * 64 + sm * 16 + lg * 4 + r;
          float p = fmaxf(fmaxf(v0, v1), v2) + bias[co];
          const int cc2 = co >> 5, q = (co >> 3) & 3, e = co & 7;
          const int row_g = (t + 1) * 5 + l15;
          h1[((size_t)(b * 16 + cc2) * 1026 + (t + 1)) * 160 + l15 * 32 +
             (q ^ ((row_g >> 1) & 3)) * 8 + e] = f2bf(fmaxf(p, 0.f));
        }
      }
    }
}

// ---------------------------------------------------------------------------
// conv2 (512->512, 3x3, pad t +-1) + pool3 + relu, counted-vmcnt pipeline ->
// emb_in fp32 [b][t][512].
// ---------------------------------------------------------------------------
__global__ __launch_bounds__(512) void conv2_kernel(
    const short* __restrict__ h1, const short* __restrict__ wt2,
    const float* __restrict__ bias, float* __restrict__ emb_in) {
  const int b = blockIdx.x >> 5;
  const int t0 = (blockIdx.x & 31) * 32;
  const int co0 = blockIdx.y * 128;
  __shared__ __align__(16) short smem2[35840];  // 71680 B
  // layout: X buf0 @0, X buf1 @5632, A buf0 @11264, A buf1 @23552 (shorts)
  const int tid = threadIdx.x;
  const int lane = tid & 63;
  const int wid = tid >> 6;
  const int wm = wid >> 1;  // 0..3 (32 co each)
  const int wn = wid & 1;   // 0..1 (48 cols each)
  const int l15 = lane & 15, lg = lane >> 4;
  const f32x4 zf = {0.f, 0.f, 0.f, 0.f};
  f32x4 acc[2][3];
#pragma unroll
  for (int i = 0; i < 2; ++i)
#pragma unroll
    for (int j = 0; j < 3; ++j) acc[i][j] = zf;
  int tl[3], dwl[3];
#pragma unroll
  for (int sn = 0; sn < 3; ++sn) {
    const int c = wn * 48 + sn * 16 + l15;
    tl[sn] = c / 3;
    dwl[sn] = c - tl[sn] * 3;
  }

  auto stageX = [&](int cc, int buf) {
    const short* xs = h1 + ((size_t)(b * 16 + cc) * 1026 + t0) * 160;
#pragma unroll
    for (int i = 0; i < 2; ++i) {
      const int v = wid + 8 * i;
      if (v < 11) gld16(xs + v * 512 + lane * 8, &smem2[buf * 5632 + v * 512]);
    }
  };
  auto stageA = [&](int cc, int g, int buf) {
#pragma unroll
    for (int i = 0; i < 3; ++i) {
      const int u = wid * 3 + i;      // 0..23, uniform 3 per wave
      const int pl = u >> 3, r = u & 7;
      gld16(wt2 + ((size_t)((cc * 9 + g * 3 + pl) * 512) + co0) * 32 +
                r * 512 + lane * 8,
            &smem2[11264 + buf * 12288 + pl * 4096 + r * 512]);
    }
  };

  stageX(0, 0);
  stageA(0, 0, 0);
  asm volatile("s_waitcnt vmcnt(0)" ::: "memory");
  __builtin_amdgcn_s_barrier();

  for (int s = 0; s < 48; ++s) {
    const int cc = s / 3, g = s - cc * 3;
    if (s < 47) {
      const int s1 = s + 1;
      const int cc1 = s1 / 3, g1 = s1 - cc1 * 3;
      stageA(cc1, g1, s1 & 1);
      if (g1 == 0) {
        stageX(cc1, cc1 & 1);
        if (wid < 3) asm volatile("s_waitcnt vmcnt(5)" ::: "memory");  // 3A+2X
        else         asm volatile("s_waitcnt vmcnt(4)" ::: "memory");  // 3A+1X
      } else {
        asm volatile("s_waitcnt vmcnt(3)" ::: "memory");               // 3A
      }
    } else {
      asm volatile("s_waitcnt vmcnt(0)" ::: "memory");
    }
    __builtin_amdgcn_s_barrier();
    const short* Xb = &smem2[(cc & 1) * 5632];
    const short* Ab = &smem2[11264 + (s & 1) * 12288];
#pragma unroll
    for (int j = 0; j < 3; ++j) {   // p = g*3+j -> dt=g, dw=j
      bf16x8 a[2];
#pragma unroll
      for (int sm = 0; sm < 2; ++sm) {
        const int co_l = wm * 32 + sm * 16 + l15;
        a[sm] = *reinterpret_cast<const bf16x8*>(
            &Ab[(j * 512 + co_l * 4 + (lg ^ ((co_l >> 1) & 3))) * 8]);
      }
#pragma unroll
      for (int sn = 0; sn < 3; ++sn) {
        const int row = (tl[sn] + g) * 5 + dwl[sn] + j;
        bf16x8 xv = *reinterpret_cast<const bf16x8*>(
            &Xb[(row * 4 + (lg ^ ((row >> 1) & 3))) * 8]);
#pragma unroll
        for (int sm = 0; sm < 2; ++sm)
          acc[sm][sn] = __builtin_amdgcn_mfma_f32_16x16x32_bf16(a[sm], xv, acc[sm][sn], 0, 0, 0);
      }
    }
    asm volatile("" ::: "memory");
    __builtin_amdgcn_s_barrier();
  }
  float(*Ds)[100] = reinterpret_cast<float(*)[100]>(smem2);  // epilogue overlay
#pragma unroll
  for (int sm = 0; sm < 2; ++sm)
#pragma unroll
    for (int sn = 0; sn < 3; ++sn)
#pragma unroll
      for (int r = 0; r < 4; ++r)
        Ds[wm * 32 + sm * 16 + lg * 4 + r][wn * 48 + sn * 16 + l15] = acc[sm][sn][r];
  __syncthreads();
  for (int e = tid; e < 4096; e += 512) {
    const int co = e & 127, tt = e >> 7;
    float m = fmaxf(fmaxf(Ds[co][tt * 3], Ds[co][tt * 3 + 1]), Ds[co][tt * 3 + 2]) + bias[co0 + co];
    emb_in[((size_t)(b * 1024) + t0 + tt) * 512 + co0 + co] = fmaxf(m, 0.f);
  }
}

// ---------------------------------------------------------------------------
// LayerNorm kernels. wave-per-row (512 cols, 8 per lane).
// ln_double: x -> emb (fp32, residual) and hs1 (bf16, GEMM A input)
// ---------------------------------------------------------------------------
__global__ __launch_bounds__(256) void ln_double_kernel(
    const float* __restrict__ x, const float* __restrict__ g0,
    const float* __restrict__ b0, const float* __restrict__ g1,
    const float* __restrict__ b1, float* __restrict__ o0, short* __restrict__ o1) {
  const int row = blockIdx.x * 4 + (threadIdx.x >> 6);
  const int lane = threadIdx.x & 63;
  const float* xr = x + (size_t)row * 512;
  float v[8];
#pragma unroll
  for (int j = 0; j < 8; ++j) v[j] = xr[j * 64 + lane];
  float s = 0;
#pragma unroll
  for (int j = 0; j < 8; ++j) s += v[j];
  s = wave_sum(s);
  const float mean = s * (1.f / 512.f);
  float q = 0;
#pragma unroll
  for (int j = 0; j < 8; ++j) { float d = v[j] - mean; q += d * d; }
  q = wave_sum(q);
  const float rs = rsqrtf(q * (1.f / 512.f) + 1e-5f);
#pragma unroll
  for (int j = 0; j < 8; ++j) {
    const int ci = j * 64 + lane;
    float e = (v[j] - mean) * rs * g0[ci] + b0[ci];
    o0[(size_t)row * 512 + ci] = e;
    v[j] = e;
  }
  s = 0;
#pragma unroll
  for (int j = 0; j < 8; ++j) s += v[j];
  s = wave_sum(s);
  const float mean2 = s * (1.f / 512.f);
  q = 0;
#pragma unroll
  for (int j = 0; j < 8; ++j) { float d = v[j] - mean2; q += d * d; }
  q = wave_sum(q);
  const float rs2 = rsqrtf(q * (1.f / 512.f) + 1e-5f);
#pragma unroll
  for (int j = 0; j < 8; ++j) {
    const int ci = j * 64 + lane;
    o1[(size_t)row * 512 + ci] = f2bf((v[j] - mean2) * rs2 * g1[ci] + b1[ci]);
  }
}

__global__ __launch_bounds__(256) void ln_kernel(
    const float* __restrict__ x, const float* __restrict__ g,
    const float* __restrict__ b, short* __restrict__ o) {
  const int row = blockIdx.x * 4 + (threadIdx.x >> 6);
  const int lane = threadIdx.x & 63;
  const float* xr = x + (size_t)row * 512;
  float v[8];
#pragma unroll
  for (int j = 0; j < 8; ++j) v[j] = xr[j * 64 + lane];
  float s = 0;
#pragma unroll
  for (int j = 0; j < 8; ++j) s += v[j];
  s = wave_sum(s);
  const float mean = s * (1.f / 512.f);
  float q = 0;
#pragma unroll
  for (int j = 0; j < 8; ++j) { float d = v[j] - mean; q += d * d; }
  q = wave_sum(q);
  const float rs = rsqrtf(q * (1.f / 512.f) + 1e-5f);
#pragma unroll
  for (int j = 0; j < 8; ++j) {
    const int ci = j * 64 + lane;
    o[(size_t)row * 512 + ci] = f2bf((v[j] - mean) * rs * g[ci] + b[ci]);
  }
}

// ---------------------------------------------------------------------------
// 1D neighborhood attention (K=7) with rpb. qkv fp32 [b][t][1536]
// (q at +0 pre-scaled 1/8, k at +512, v at +1024). wave per (b,h,t); lane=d.
// ctx output bf16 (feeds attn-out GEMM).
// ---------------------------------------------------------------------------
__global__ __launch_bounds__(256) void na1d_kernel(
    const float* __restrict__ qkv, const float* __restrict__ rpb,
    short* __restrict__ ctx) {
  const int W = blockIdx.x * 4 + (threadIdx.x >> 6);
  const int lane = threadIdx.x & 63;
  const int b = W >> 13, h = (W >> 10) & 7, t = W & 1023;
  int ni = t - 3;
  ni = ni < 0 ? 0 : (ni > 1017 ? 1017 : ni);
  const float qv = qkv[((size_t)(b * 1024) + t) * 1536 + h * 64 + lane];
  const float* kb = qkv + 512 + ((size_t)(b * 1024) + ni) * 1536 + h * 64;
  float s[7];
#pragma unroll
  for (int j = 0; j < 7; ++j) {
    float pd = qv * kb[j * 1536 + lane];
    pd = wave_sum(pd);
    s[j] = pd + rpb[h * 13 + (ni + j - t + 6)];
  }
  float mx = s[0];
#pragma unroll
  for (int j = 1; j < 7; ++j) mx = fmaxf(mx, s[j]);
  float den = 0;
#pragma unroll
  for (int j = 0; j < 7; ++j) { s[j] = expf(s[j] - mx); den += s[j]; }
  const float inv = 1.f / den;
  const float* vb = qkv + 1024 + ((size_t)(b * 1024) + ni) * 1536 + h * 64;
  float o = 0;
#pragma unroll
  for (int j = 0; j < 7; ++j) o += s[j] * vb[j * 1536 + lane];
  ctx[((size_t)(b * 1024) + t) * 512 + h * 64 + lane] = f2bf(o * inv);
}

// ---------------------------------------------------------------------------
// Transformer GEMM, bf16 A: C[M=4096][N] = A[M][K](bf16) x Wt[N][K](bf16).
// Tile 128x64, 4 waves 2x2, BK=64, counted-vmcnt double-buffer, gld16 staging
// with consumer-side XOR pre-swizzle. LDS 48KB -> 3 blocks/CU.
// EPI: 2 = bias+gelu -> bf16 out, 3 = bias+residual -> f32,
//      4 = bias, *0.125 if n<512 -> f32 (fused qkv).
// ---------------------------------------------------------------------------
template <int EPI>
__global__ __launch_bounds__(256) void gemm_bf(
    const short* __restrict__ A, const short* __restrict__ Wt,
    const float* __restrict__ bias, const float* __restrict__ res,
    void* __restrict__ Cv, int K, int N) {
  const int m0 = blockIdx.x * 128, n0 = blockIdx.y * 64;
  __shared__ short Asm[2][8192];   // [128 rows][64 k] linear, 16KB each
  __shared__ short Bsm[2][4096];   // [64 rows][64 k] linear, 8KB each
  const int tid = threadIdx.x;
  const int wid = tid >> 6, lane = tid & 63;
  const int wm = wid >> 1, wn = wid & 1;
  const int l15 = lane & 15, lg = lane >> 4;
  const int srow = lane >> 3, su = lane & 7;          // staging roles
  const int ssw = (su ^ srow) << 3;                   // pre-swizzled k-unit (shorts)
  const f32x4 zf = {0.f, 0.f, 0.f, 0.f};
  f32x4 acc[4][2];
#pragma unroll
  for (int i = 0; i < 4; ++i) { acc[i][0] = zf; acc[i][1] = zf; }

  auto stage = [&](int k0, int buf) {
#pragma unroll
    for (int i = 0; i < 4; ++i) {                      // A: rows 8/call
      const int r0 = (wid * 4 + i) * 8;                // 0,8,...,120
      gld16(A + (size_t)(m0 + r0 + srow) * K + k0 + ssw, &Asm[buf][r0 * 64]);
    }
#pragma unroll
    for (int i = 0; i < 2; ++i) {                      // B: rows 8/call
      const int r0 = (wid * 2 + i) * 8;                // 0,8,...,56
      gld16(Wt + (size_t)(n0 + r0 + srow) * K + k0 + ssw, &Bsm[buf][r0 * 64]);
    }
  };

  const int S = K >> 6;
  stage(0, 0);
  asm volatile("s_waitcnt vmcnt(0)" ::: "memory");
  __builtin_amdgcn_s_barrier();

  for (int s = 0; s < S; ++s) {
    if (s < S - 1) {
      stage((s + 1) << 6, (s + 1) & 1);
      asm volatile("s_waitcnt vmcnt(6)" ::: "memory");
    } else {
      asm volatile("s_waitcnt vmcnt(0)" ::: "memory");
    }
    __builtin_amdgcn_s_barrier();
    const short* Ab = Asm[s & 1];
    const short* Bb = Bsm[s & 1];
#pragma unroll
    for (int kk = 0; kk < 2; ++kk) {
      const int u = kk * 4 + lg;
      bf16x8 bfr[2];
#pragma unroll
      for (int sn = 0; sn < 2; ++sn) {
        const int rn = wn * 32 + sn * 16 + l15;
        bfr[sn] = *reinterpret_cast<const bf16x8*>(&Bb[rn * 64 + ((u ^ (rn & 7)) << 3)]);
      }
#pragma unroll
      for (int sm = 0; sm < 4; ++sm) {
        const int rm = wm * 64 + sm * 16 + l15;
        bf16x8 a = *reinterpret_cast<const bf16x8*>(&Ab[rm * 64 + ((u ^ (rm & 7)) << 3)]);
#pragma unroll
        for (int sn = 0; sn < 2; ++sn)
          acc[sm][sn] = __builtin_amdgcn_mfma_f32_16x16x32_bf16(a, bfr[sn], acc[sm][sn], 0, 0, 0);
      }
    }
    asm volatile("" ::: "memory");
    __builtin_amdgcn_s_barrier();
  }
#pragma unroll
  for (int sm = 0; sm < 4; ++sm)
#pragma unroll
    for (int sn = 0; sn < 2; ++sn)
#pragma unroll
      for (int r = 0; r < 4; ++r) {
        const int m = m0 + wm * 64 + sm * 16 + lg * 4 + r;
        const int n = n0 + wn * 32 + sn * 16 + l15;
        float val = acc[sm][sn][r] + bias[n];
        if (EPI == 2) {
          val = 0.5f * val * (1.f + erff(val * 0.70710678f));
          ((short*)Cv)[(size_t)m * N + n] = f2bf(val);
        } else {
          if (EPI == 3) val += res[(size_t)m * N + n];
          if (EPI == 4 && n < 512) val *= 0.125f;
          ((float*)Cv)[(size_t)m * N + n] = val;
        }
      }
}

// ---------------------------------------------------------------------------
extern "C" void kernel_launch(void* const* d_in, const int* in_sizes, int n_in,
                              void* d_out, int out_size, void* d_ws, size_t ws_size,
                              hipStream_t stream) {
  (void)in_sizes; (void)n_in; (void)out_size;
  const float* x        = (const float*)d_in[0];
  const float* conv0_w  = (const float*)d_in[1];
  const float* conv0_b  = (const float*)d_in[2];
  const float* conv1_w  = (const float*)d_in[3];
  const float* conv1_b  = (const float*)d_in[4];
  const float* conv2_w  = (const float*)d_in[5];
  const float* conv2_b  = (const float*)d_in[6];
  const float* emb_ln_g = (const float*)d_in[7];
  const float* emb_ln_b = (const float*)d_in[8];
  const float* q_w  = (const float*)d_in[9];
  const float* q_b  = (const float*)d_in[10];
  const float* k_w  = (const float*)d_in[11];
  const float* k_b  = (const float*)d_in[12];
  const float* v_w  = (const float*)d_in[13];
  const float* v_b  = (const float*)d_in[14];
  const float* rpb  = (const float*)d_in[15];
  const float* ao_w = (const float*)d_in[16];
  const float* ao_b = (const float*)d_in[17];
  const float* ln1_g = (const float*)d_in[18];
  const float* ln1_b = (const float*)d_in[19];
  const float* ln2_g = (const float*)d_in[20];
  const float* ln2_b = (const float*)d_in[21];
  const float* m1_w = (const float*)d_in[22];
  const float* m1_b = (const float*)d_in[23];
  const float* m2_w = (const float*)d_in[24];
  const float* m2_b = (const float*)d_in[25];

  char* ws = (char*)d_ws;
  size_t off = 0;
  auto alloc = [&](size_t bytes) -> char* {
    char* p = ws + off;
    off += (bytes + 255) & ~(size_t)255;
    return p;
  };
  short* h0   = (short*)alloc(4ull * 8 * 1024 * 896 * 2);     // 58.7 MB
  short* h1   = (short*)alloc(4ull * 16 * 1026 * 160 * 2);    // 21.0 MB
  float* embi = (float*)alloc(4ull * 1024 * 512 * 4);
  float* emb  = (float*)alloc(4ull * 1024 * 512 * 4);
  short* hs1  = (short*)alloc(4ull * 1024 * 512 * 2);         // bf16 GEMM A
  float* qkv  = (float*)alloc(4ull * 1024 * 1536 * 4);        // 25.2 MB
  short* ctx  = (short*)alloc(4ull * 1024 * 512 * 2);         // bf16
  float* hs   = (float*)alloc(4ull * 1024 * 512 * 4);
  short* wt1  = (short*)alloc(512ull * 12 * 256 * 2);
  short* wt2  = (short*)alloc(512ull * 9 * 512 * 2);
  short* wtqkv = (short*)alloc(1536ull * 512 * 2);
  short* wtao = (short*)alloc(512ull * 512 * 2);
  short* wtm1 = (short*)alloc(2048ull * 512 * 2);
  short* wtm2 = (short*)alloc(512ull * 2048 * 2);
  float* qkvb = (float*)alloc(1536ull * 4);
  if (ws_size < off) return;  // fail visibly (poisoned output) instead of OOB
  short* mid  = (short*)h0;   // bf16 [4096][2048] = 16.8MB <= 58.7, h0 dead
  short* ln2o = (short*)embi; // bf16 [4096][512] = 4.2MB <= 8.4, embi dead
  float* outp = (float*)d_out;

  prep_w1<<<512, 256, 0, stream>>>(conv1_w, wt1);
  prep_w2<<<512, 256, 0, stream>>>(conv2_w, wt2);
  prep_all<<<3142, 256, 0, stream>>>(q_w, k_w, v_w, ao_w, m1_w, m2_w,
                                     q_b, k_b, v_b,
                                     wtqkv, wtao, wtm1, wtm2, qkvb, h1);

  conv0_kernel<<<4096, 256, 0, stream>>>(x, conv0_w, conv0_b, h0);
  conv1_kernel<<<dim3(128, 4), 512, 0, stream>>>(h0, wt1, conv1_b, h1);
  conv2_kernel<<<dim3(128, 4), 512, 0, stream>>>(h1, wt2, conv2_b, embi);
  ln_double_kernel<<<1024, 256, 0, stream>>>(embi, emb_ln_g, emb_ln_b, ln1_g, ln1_b, emb, hs1);
  gemm_bf<4><<<dim3(32, 24), 256, 0, stream>>>(hs1, wtqkv, qkvb, nullptr, qkv, 512, 1536);
  na1d_kernel<<<8192, 256, 0, stream>>>(qkv, rpb, ctx);
  gemm_bf<3><<<dim3(32, 8), 256, 0, stream>>>(ctx, wtao, ao_b, emb, hs, 512, 512);
  ln_kernel<<<1024, 256, 0, stream>>>(hs, ln2_g, ln2_b, ln2o);
  gemm_bf<2><<<dim3(32, 32), 256, 0, stream>>>(ln2o, wtm1, m1_b, nullptr, mid, 512, 2048);
  gemm_bf<3><<<dim3(32, 8), 256, 0, stream>>>(mid, wtm2, m2_b, hs, outp, 2048, 512);
}